// Round 1
// baseline (154.750 us; speedup 1.0000x reference)
//
#include <hip/hip_runtime.h>
#include <math.h>

#define BB 8
#define CC 64
#define NN 4096
#define CI 8
#define GAMMA 0.1f
// log2(e) / sqrt(8)
#define SC 0.509913987f
// (1/ln2) = 1.44269504089f ; 1.44269504089/2.82842712475 = 0.51011...
// recompute precisely below in host-independent constexpr

__device__ __forceinline__ float fast_exp2(float x) {
    return __builtin_amdgcn_exp2f(x);
}

__global__ void zero_kernel(float* __restrict__ p, int n) {
    int i = blockIdx.x * blockDim.x + threadIdx.x;
    if (i < n) p[i] = 0.0f;
}

// Thread per (b, n): compute q,k,v[b][:][n].
// qv layout: [b][n][16] = {q0..q7, v0..v7}  (float4-friendly for LDS staging)
// kb layout: [b][i][N]
__global__ __launch_bounds__(256) void qkv_kernel(
        const float* __restrict__ x,
        const float* __restrict__ Wq, const float* __restrict__ Wk,
        const float* __restrict__ Wv,
        float* __restrict__ qv, float* __restrict__ kb) {
    __shared__ float sW[3 * CI * CC];   // 6 KB
    int t = threadIdx.x;
    for (int i = t; i < CI * CC; i += blockDim.x) {
        sW[i]             = Wq[i];
        sW[CI * CC + i]   = Wk[i];
        sW[2 * CI * CC + i] = Wv[i];
    }
    __syncthreads();
    int gid = blockIdx.x * blockDim.x + t;   // over BB*NN = 32768
    int b = gid >> 12;
    int n = gid & (NN - 1);
    const float* xp = x + ((size_t)b * CC) * NN + n;
    float qa[CI], ka[CI], va[CI];
#pragma unroll
    for (int i = 0; i < CI; ++i) { qa[i] = 0.f; ka[i] = 0.f; va[i] = 0.f; }
    for (int c = 0; c < CC; ++c) {
        float xv = xp[(size_t)c * NN];
#pragma unroll
        for (int i = 0; i < CI; ++i) {
            qa[i] = fmaf(sW[i * CC + c], xv, qa[i]);
            ka[i] = fmaf(sW[CI * CC + i * CC + c], xv, ka[i]);
            va[i] = fmaf(sW[2 * CI * CC + i * CC + c], xv, va[i]);
        }
    }
    float* qvp = qv + ((size_t)b * NN + n) * 16;
#pragma unroll
    for (int i = 0; i < CI; ++i) { qvp[i] = qa[i]; qvp[8 + i] = va[i]; }
    float* kp = kb + ((size_t)b * CI) * NN + n;
#pragma unroll
    for (int i = 0; i < CI; ++i) kp[(size_t)i * NN] = ka[i];
}

// Attention core. No max-subtraction needed: |scores| < ~2, exp() is safe and
// softmax is shift-invariant, so att[n,m] = e(s_nm)/sum_n e(s_nm).
// Grid: (m-tiles = 4, n-chunks = 32, B). Block = 256 threads, MT=4 columns each.
// attab layout: [b][9][N] -> rows 0..7 = sum_n e*v_i, row 8 = sum_n e.
#define MT 4
#define NCHUNK 128
__global__ __launch_bounds__(256) void att_kernel(
        const float* __restrict__ qv, const float* __restrict__ kb,
        float* __restrict__ attab) {
    __shared__ float sqv[NCHUNK * 16];   // 8 KB
    const int t = threadIdx.x;
    const int b = blockIdx.z;
    const int n0 = blockIdx.y * NCHUNK;
    const int m0 = blockIdx.x * (256 * MT);

    // stage q/v chunk: 2048 floats = 512 float4
    const float4* src = (const float4*)(qv + ((size_t)b * NN + n0) * 16);
    float4* dst = (float4*)sqv;
    for (int i = t; i < NCHUNK * 4; i += 256) dst[i] = src[i];
    __syncthreads();

    // exp2-folded scale: exp(s/sqrt(8)) = exp2(s * log2(e)/sqrt(8))
    const float scale = 1.44269504088896f * 0.35355339059327f; // log2e * 1/sqrt(8)

    float kr[MT][CI];
    int mm[MT];
#pragma unroll
    for (int j = 0; j < MT; ++j) {
        int m = m0 + t + 256 * j;
        mm[j] = m;
#pragma unroll
        for (int i = 0; i < CI; ++i)
            kr[j][i] = kb[((size_t)b * CI + i) * NN + m] * scale;
    }

    float acc[MT][CI];
    float es[MT];
#pragma unroll
    for (int j = 0; j < MT; ++j) {
        es[j] = 0.f;
#pragma unroll
        for (int i = 0; i < CI; ++i) acc[j][i] = 0.f;
    }

    for (int n = 0; n < NCHUNK; ++n) {
        const float* p = sqv + n * 16;          // same addr all lanes: broadcast
        float4 q0 = *(const float4*)(p);
        float4 q1 = *(const float4*)(p + 4);
        float4 v0 = *(const float4*)(p + 8);
        float4 v1 = *(const float4*)(p + 12);
#pragma unroll
        for (int j = 0; j < MT; ++j) {
            float s = q0.x * kr[j][0];
            s = fmaf(q0.y, kr[j][1], s);
            s = fmaf(q0.z, kr[j][2], s);
            s = fmaf(q0.w, kr[j][3], s);
            s = fmaf(q1.x, kr[j][4], s);
            s = fmaf(q1.y, kr[j][5], s);
            s = fmaf(q1.z, kr[j][6], s);
            s = fmaf(q1.w, kr[j][7], s);
            float e = fast_exp2(s);
            es[j] += e;
            acc[j][0] = fmaf(e, v0.x, acc[j][0]);
            acc[j][1] = fmaf(e, v0.y, acc[j][1]);
            acc[j][2] = fmaf(e, v0.z, acc[j][2]);
            acc[j][3] = fmaf(e, v0.w, acc[j][3]);
            acc[j][4] = fmaf(e, v1.x, acc[j][4]);
            acc[j][5] = fmaf(e, v1.y, acc[j][5]);
            acc[j][6] = fmaf(e, v1.z, acc[j][6]);
            acc[j][7] = fmaf(e, v1.w, acc[j][7]);
        }
    }

#pragma unroll
    for (int j = 0; j < MT; ++j) {
        float* ap = attab + (size_t)b * 9 * NN + mm[j];
#pragma unroll
        for (int i = 0; i < CI; ++i) atomicAdd(ap + (size_t)i * NN, acc[j][i]);
        atomicAdd(ap + (size_t)8 * NN, es[j]);
    }
}

// Thread per (b,m): normalize, project with Wout, residual-add.
__global__ __launch_bounds__(256) void out_kernel(
        const float* __restrict__ x, const float* __restrict__ Wout,
        const float* __restrict__ attab, float* __restrict__ out) {
    __shared__ float sW[CC * CI];   // 2 KB
    int t = threadIdx.x;
    for (int i = t; i < CC * CI; i += blockDim.x) sW[i] = Wout[i];
    __syncthreads();
    int gid = blockIdx.x * blockDim.x + t;   // over BB*NN
    int b = gid >> 12;
    int m = gid & (NN - 1);
    const float* ap = attab + (size_t)b * 9 * NN + m;
    float inv = 1.0f / ap[(size_t)8 * NN];
    float ao[CI];
#pragma unroll
    for (int i = 0; i < CI; ++i) ao[i] = ap[(size_t)i * NN] * inv;
    const float* xp = x + ((size_t)b * CC) * NN + m;
    float* op = out + ((size_t)b * CC) * NN + m;
    for (int c = 0; c < CC; ++c) {
        float s = 0.f;
#pragma unroll
        for (int i = 0; i < CI; ++i) s = fmaf(sW[c * CI + i], ao[i], s);
        op[(size_t)c * NN] = xp[(size_t)c * NN] + GAMMA * s;
    }
}

extern "C" void kernel_launch(void* const* d_in, const int* in_sizes, int n_in,
                              void* d_out, int out_size, void* d_ws, size_t ws_size,
                              hipStream_t stream) {
    const float* x    = (const float*)d_in[0];
    const float* Wq   = (const float*)d_in[1];
    const float* Wk   = (const float*)d_in[2];
    const float* Wv   = (const float*)d_in[3];
    const float* Wout = (const float*)d_in[4];
    float* out = (float*)d_out;
    float* ws  = (float*)d_ws;

    // ws layout (floats): qv [B][N][16] = 524288 | kb [B][8][N] = 262144 |
    //                     attab [B][9][N] = 294912. Total ~4.3 MB.
    float* qv    = ws;
    float* kb    = ws + (size_t)BB * NN * 16;
    float* attab = kb + (size_t)BB * CI * NN;
    const int attab_n = BB * 9 * NN;

    zero_kernel<<<(attab_n + 255) / 256, 256, 0, stream>>>(attab, attab_n);
    qkv_kernel<<<(BB * NN) / 256, 256, 0, stream>>>(x, Wq, Wk, Wv, qv, kb);
    att_kernel<<<dim3(NN / (256 * MT), NN / NCHUNK, BB), 256, 0, stream>>>(qv, kb, attab);
    out_kernel<<<(BB * NN) / 256, 256, 0, stream>>>(x, Wout, attab, out);
}